// Round 5
// baseline (284.597 us; speedup 1.0000x reference)
//
#include <hip/hip_runtime.h>
#include <math.h>

#define SEQ 2048
#define DIM 1024
#define HD  128
#define NB  8
#define M_TOT (NB * SEQ)   // 16384

typedef __attribute__((ext_vector_type(8))) short   short8;   // 8 x bf16 (4 VGPRs)
typedef __attribute__((ext_vector_type(4))) float   floatx4;  // MFMA acc

__device__ __forceinline__ unsigned short f2bf(float f) {
    unsigned u = __builtin_bit_cast(unsigned, f);
    u += 0x7FFFu + ((u >> 16) & 1u);
    return (unsigned short)(u >> 16);
}
__device__ __forceinline__ float bf2f(unsigned short h) {
    unsigned u = ((unsigned)h) << 16;
    return __builtin_bit_cast(float, u);
}
__device__ __forceinline__ void async16(const void* g, void* l) {
    __builtin_amdgcn_global_load_lds(
        (const __attribute__((address_space(1))) unsigned int*)g,
        (__attribute__((address_space(3))) unsigned int*)l, 16, 0, 0);
}

#define MFMA16(a, b, c) __builtin_amdgcn_mfma_f32_16x16x32_bf16((a), (b), (c), 0, 0, 0)

// ---------------------------------------------------------------------------
// Kernel 0: W -> Wt (transposed, bf16 hi/lo split).  Wt[mat][n=128][k=1024]
// ---------------------------------------------------------------------------
__global__ __launch_bounds__(256) void wt_prep(
    const float* __restrict__ Wq, const float* __restrict__ Wk, const float* __restrict__ Wv,
    unsigned short* __restrict__ Wth, unsigned short* __restrict__ Wtl)
{
    int idx = blockIdx.x * 256 + threadIdx.x;       // [mat][n][k] flat
    int k   = idx & 1023;
    int n   = (idx >> 10) & 127;
    int mat = idx >> 17;
    const float* W = (mat == 0) ? Wq : (mat == 1) ? Wk : Wv;
    float v = W[k * HD + n];
    unsigned short hi = f2bf(v);
    Wth[idx] = hi;
    Wtl[idx] = f2bf(v - bf2f(hi));
}

// ---------------------------------------------------------------------------
// Kernel 1: QKV projection — barrier-free, LDS-free K-loop (AITER-style).
// grid = (3 mats, 256 mtiles), 256 thr, 4 waves.  BM=64, BN=128, BK=32.
// Wave w: mh=w&1 (m-frags 2mh,2mh+1), nh=w>>1 (n-frags nh*4..nh*4+3).
// A (x): direct global->VGPR in MFMA A-layout, hi/lo split in regs,
//        double-buffered across k-iters (hides HBM latency; no vmcnt(0)).
// B (Wt): direct global->VGPR short8 (L2-hot, 1.5 MB working set), JIT load
//        hidden behind the split VALU.  Q,K: bf16x3; V: hi*hi only.
// ---------------------------------------------------------------------------
__global__ __launch_bounds__(256) void qkv_gemm(
    const float* __restrict__ x,
    const unsigned short* __restrict__ Wth, const unsigned short* __restrict__ Wtl,
    const float* __restrict__ bq, const float* __restrict__ bk, const float* __restrict__ bv,
    unsigned short* __restrict__ Qh, unsigned short* __restrict__ Ql,
    unsigned short* __restrict__ Kh, unsigned short* __restrict__ Kl,
    unsigned short* __restrict__ Vt)
{
    const int t    = threadIdx.x;
    const int lane = t & 63;
    const int w    = t >> 6;
    const int lrow = lane & 15;
    const int quad = lane >> 4;

    const int mat = blockIdx.x;                     // 0=Q 1=K 2=V
    const int R0  = blockIdx.y * 64;
    const int mh  = w & 1;
    const int nh  = w >> 1;

    const unsigned short* Wh = Wth + (size_t)mat * (HD * DIM);
    const unsigned short* Wl = Wtl + (size_t)mat * (HD * DIM);

    const float* xr[2];
    #pragma unroll
    for (int mi = 0; mi < 2; ++mi)
        xr[mi] = x + (size_t)(R0 + (2 * mh + mi) * 16 + lrow) * DIM + quad * 8;
    const unsigned short* wbh[4];
    const unsigned short* wbl[4];
    #pragma unroll
    for (int ni = 0; ni < 4; ++ni) {
        size_t off = (size_t)((nh * 4 + ni) * 16 + lrow) * DIM + quad * 8;
        wbh[ni] = Wh + off;
        wbl[ni] = Wl + off;
    }

    floatx4 acc[2][4];
    const floatx4 zf = {0.f, 0.f, 0.f, 0.f};
    #pragma unroll
    for (int i = 0; i < 2; ++i)
        #pragma unroll
        for (int j = 0; j < 4; ++j) acc[i][j] = zf;

    float4 A[2][4];                                 // [buf][mi*2+half] fp32 x-frags

    auto loadA = [&](int k, int buf) {
        #pragma unroll
        for (int mi = 0; mi < 2; ++mi) {
            A[buf][mi * 2 + 0] = *(const float4*)(xr[mi] + k);
            A[buf][mi * 2 + 1] = *(const float4*)(xr[mi] + k + 4);
        }
    };

    auto compute = [&](int k, int buf) {
        // B loads issued first; their ~L2 latency hides behind the split VALU
        short8 BH[4], BL[4];
        #pragma unroll
        for (int ni = 0; ni < 4; ++ni) {
            BH[ni] = *(const short8*)(wbh[ni] + k);
            if (mat < 2) BL[ni] = *(const short8*)(wbl[ni] + k);
        }
        short8 ah[2], al[2];
        #pragma unroll
        for (int mi = 0; mi < 2; ++mi) {
            float xv[8] = {A[buf][mi*2].x,   A[buf][mi*2].y,   A[buf][mi*2].z,   A[buf][mi*2].w,
                           A[buf][mi*2+1].x, A[buf][mi*2+1].y, A[buf][mi*2+1].z, A[buf][mi*2+1].w};
            #pragma unroll
            for (int i = 0; i < 8; ++i) {
                unsigned short h = f2bf(xv[i]);
                ah[mi][i] = (short)h;
                al[mi][i] = (short)f2bf(xv[i] - bf2f(h));
            }
        }
        #pragma unroll
        for (int ni = 0; ni < 4; ++ni) {
            #pragma unroll
            for (int mi = 0; mi < 2; ++mi)
                acc[mi][ni] = MFMA16(ah[mi], BH[ni], acc[mi][ni]);
            if (mat < 2) {                          // uniform branch
                #pragma unroll
                for (int mi = 0; mi < 2; ++mi) {
                    acc[mi][ni] = MFMA16(ah[mi], BL[ni], acc[mi][ni]);
                    acc[mi][ni] = MFMA16(al[mi], BH[ni], acc[mi][ni]);
                }
            }
        }
    };

    loadA(0, 0);
    for (int it = 0; it < 32; it += 2) {
        if (it + 1 < 32) loadA((it + 1) * 32, 1);   // prefetch next A (HBM)
        compute(it * 32, 0);
        if (it + 2 < 32) loadA((it + 2) * 32, 0);
        compute((it + 1) * 32, 1);
    }

    // epilogue
    const float* bias = (mat == 0) ? bq : (mat == 1) ? bk : bv;
    #pragma unroll
    for (int ni = 0; ni < 4; ++ni) {
        int col = (nh * 4 + ni) * 16 + lrow;
        float bval = bias[col];
        #pragma unroll
        for (int mi = 0; mi < 2; ++mi) {
            #pragma unroll
            for (int reg = 0; reg < 4; ++reg) {
                int gm = R0 + (2 * mh + mi) * 16 + quad * 4 + reg;
                float v = acc[mi][ni][reg] + bval;
                if (mat == 0) {
                    v *= 32.0f;                     // fold sqrt(D)
                    unsigned short h = f2bf(v);
                    Qh[(size_t)gm * HD + col] = h;
                    Ql[(size_t)gm * HD + col] = f2bf(v - bf2f(h));
                } else if (mat == 1) {
                    unsigned short h = f2bf(v);
                    Kh[(size_t)gm * HD + col] = h;
                    Kl[(size_t)gm * HD + col] = f2bf(v - bf2f(h));
                } else {
                    int b = gm >> 11, s = gm & 2047;
                    Vt[((size_t)b * HD + col) * SEQ + s] = f2bf(v);
                }
            }
        }
    }
}

// ---------------------------------------------------------------------------
// Kernel 2: causal flash attention, optionally split-K over key tiles.
// split=1: grid 1024, idx -> b=idx&7, h=(idx>>3)&1, s=63-(idx>>4);
//          block h covers tile range [h?Th:0, h?T:Th), writes unnormalized
//          partial O + (M,L) per row.  split=0: grid 512, full range, final.
// Within a block: 4 waves = 2 row-halves (mh) x 2 key-halves (kh) with
// independent online softmax per kh, merged via LDS at the end.
// LDS frags: K id=nt*8+kc*2+p (0..31) | V id=32+df*2+kc | P 48+w.
// ---------------------------------------------------------------------------
__global__ __launch_bounds__(256) void flash_attn(
    const unsigned short* __restrict__ Qh, const unsigned short* __restrict__ Ql,
    const unsigned short* __restrict__ Kh, const unsigned short* __restrict__ Kl,
    const unsigned short* __restrict__ Vt, float* __restrict__ out,
    float* __restrict__ Opart, float* __restrict__ ML, int split)
{
    __shared__ short lds[52 * 512];                 // 52 KB

    const int t    = threadIdx.x;
    const int lane = t & 63;
    const int w    = t >> 6;
    const int lrow = lane & 15;
    const int quad = lane >> 4;

    const int idx = blockIdx.x;
    const int b   = idx & 7;
    const int h   = split ? ((idx >> 3) & 1) : 0;
    const int s   = split ? (63 - (idx >> 4)) : (63 - (idx >> 3));
    const int T   = (s + 2) >> 1;                   // 64-key tiles in strip
    const int Th  = (T + 1) >> 1;
    const int t0  = split ? (h ? Th : 0) : 0;
    const int t1  = split ? (h ? T : Th) : T;

    if (split && t0 >= t1) {                        // empty half (s==0,h==1)
        float* op = Opart + (size_t)idx * 4096;
        for (int i = t; i < 4096; i += 256) op[i] = 0.0f;
        if (t < 32) { ML[(idx * 32 + t) * 2] = -1e30f; ML[(idx * 32 + t) * 2 + 1] = 0.0f; }
        return;
    }

    const int mh = w & 1;
    const int kh = w >> 1;
    const int R  = s * 32 + mh * 16;                // wave's first row (batch-local)

    const size_t kbase = (size_t)b * SEQ * HD;
    const size_t vbase = (size_t)b * HD * SEQ;

    short8 qf[4][2];
    #pragma unroll
    for (int kc = 0; kc < 4; ++kc) {
        size_t off = kbase + (size_t)(R + lrow) * HD + kc * 32 + quad * 8;
        qf[kc][0] = *(const short8*)(Qh + off);
        qf[kc][1] = *(const short8*)(Ql + off);
    }

    const floatx4 zf = {0.f, 0.f, 0.f, 0.f};
    floatx4 accO[8];
    #pragma unroll
    for (int i = 0; i < 8; ++i) accO[i] = zf;
    float m_[4] = {-1e30f, -1e30f, -1e30f, -1e30f};
    float l_[4] = {0.f, 0.f, 0.f, 0.f};

    for (int it = t0; it < t1; ++it) {
        const int j0 = it * 64;
        __syncthreads();
        #pragma unroll
        for (int i = 0; i < 12; ++i) {
            int id = w * 12 + i;
            const unsigned short* src;
            if (id < 32) {                          // K frag: nt,kc,p
                int nt = id >> 3, kc = (id >> 1) & 3, p = id & 1;
                src = (p ? Kl : Kh) + kbase
                    + (size_t)(j0 + nt * 16 + lrow) * HD + kc * 32 + quad * 8;
            } else {                                // V frag: df,kc
                int v = id - 32, df = v >> 1, kc = v & 1;
                src = Vt + vbase + (size_t)(df * 16 + lrow) * SEQ
                    + j0 + kc * 32 + quad * 8;
            }
            async16(src, &lds[id * 512 + lane * 8]);
        }
        __syncthreads();

        // QK^T over my 32-key half (bf16x3)
        floatx4 S[2] = {zf, zf};
        #pragma unroll
        for (int ntl = 0; ntl < 2; ++ntl) {
            int nt = kh * 2 + ntl;
            #pragma unroll
            for (int kc = 0; kc < 4; ++kc) {
                short8 khf = *(short8*)&lds[(nt * 8 + kc * 2 + 0) * 512 + lane * 8];
                short8 klf = *(short8*)&lds[(nt * 8 + kc * 2 + 1) * 512 + lane * 8];
                S[ntl] = MFMA16(qf[kc][0], khf, S[ntl]);
                S[ntl] = MFMA16(qf[kc][0], klf, S[ntl]);
                S[ntl] = MFMA16(qf[kc][1], khf, S[ntl]);
            }
        }
        // causal mask (only the strip's last tile triggers this)
        if (j0 + kh * 32 + 31 > R) {
            #pragma unroll
            for (int ntl = 0; ntl < 2; ++ntl) {
                int key = j0 + (kh * 2 + ntl) * 16 + lrow;
                #pragma unroll
                for (int reg = 0; reg < 4; ++reg) {
                    if (key > R + quad * 4 + reg) S[ntl][reg] = -INFINITY;
                }
            }
        }
        // online softmax (independent per key-half)
        float alpha[4];
        #pragma unroll
        for (int reg = 0; reg < 4; ++reg) {
            float mx = fmaxf(S[0][reg], S[1][reg]);
            #pragma unroll
            for (int hh = 1; hh < 16; hh <<= 1) mx = fmaxf(mx, __shfl_xor(mx, hh));
            float mnew = fmaxf(fmaxf(m_[reg], mx), -1e30f);
            alpha[reg] = __expf(m_[reg] - mnew);
            m_[reg] = mnew;
            float p0 = __expf(S[0][reg] - mnew);
            float p1 = __expf(S[1][reg] - mnew);
            S[0][reg] = p0; S[1][reg] = p1;
            float ls = p0 + p1;
            #pragma unroll
            for (int hh = 1; hh < 16; hh <<= 1) ls += __shfl_xor(ls, hh);
            l_[reg] = l_[reg] * alpha[reg] + ls;
        }
        #pragma unroll
        for (int i = 0; i < 8; ++i)
            #pragma unroll
            for (int reg = 0; reg < 4; ++reg) accO[i][reg] *= alpha[reg];

        // P: C-layout -> A-layout LDS (same-wave round trip, no barrier)
        #pragma unroll
        for (int ntl = 0; ntl < 2; ++ntl) {
            #pragma unroll
            for (int reg = 0; reg < 4; ++reg) {
                int kloc = ntl * 16 + lrow;          // 0..31
                int jj = kloc & 7, q2 = (kloc >> 3) & 3;
                int lane2 = (quad * 4 + reg) + (q2 << 4);
                lds[(48 + w) * 512 + lane2 * 8 + jj] = (short)f2bf(S[ntl][reg]);
            }
        }
        short8 pf = *(short8*)&lds[(48 + w) * 512 + lane * 8];
        #pragma unroll
        for (int df = 0; df < 8; ++df) {
            short8 vf = *(short8*)&lds[(32 + df * 2 + kh) * 512 + lane * 8];
            accO[df] = MFMA16(pf, vf, accO[df]);
        }
    }

    // ---- merge the two key-halves (once per block) ----
    __syncthreads();
    float* fl   = (float*)lds;
    float* Obuf = fl;                               // [32][128]
    float* mlb  = fl + 4096;                        // [kh][mh][row][2]
    if (lrow == 0) {
        #pragma unroll
        for (int reg = 0; reg < 4; ++reg) {
            int row = quad * 4 + reg;
            mlb[((kh * 2 + mh) * 16 + row) * 2 + 0] = m_[reg];
            mlb[((kh * 2 + mh) * 16 + row) * 2 + 1] = l_[reg];
        }
    }
    __syncthreads();
    float myw[4], Mrow[4], Drow[4];
    #pragma unroll
    for (int reg = 0; reg < 4; ++reg) {
        int row = quad * 4 + reg;
        float mo  = mlb[(((1 - kh) * 2 + mh) * 16 + row) * 2 + 0];
        float lo_ = mlb[(((1 - kh) * 2 + mh) * 16 + row) * 2 + 1];
        float M = fmaxf(m_[reg], mo);
        float d = l_[reg] * __expf(m_[reg] - M) + lo_ * __expf(mo - M);
        Mrow[reg] = M; Drow[reg] = d;
        myw[reg] = split ? __expf(m_[reg] - M) : (__expf(m_[reg] - M) / d);
    }
    if (kh == 0) {
        #pragma unroll
        for (int df = 0; df < 8; ++df)
            #pragma unroll
            for (int reg = 0; reg < 4; ++reg)
                Obuf[(mh * 16 + quad * 4 + reg) * 128 + df * 16 + lrow] =
                    accO[df][reg] * myw[reg];
    }
    __syncthreads();
    if (kh == 1) {
        if (split) {
            float* op = Opart + (size_t)idx * 4096;
            #pragma unroll
            for (int df = 0; df < 8; ++df) {
                #pragma unroll
                for (int reg = 0; reg < 4; ++reg) {
                    int row = mh * 16 + quad * 4 + reg;
                    op[row * 128 + df * 16 + lrow] =
                        Obuf[row * 128 + df * 16 + lrow] + accO[df][reg] * myw[reg];
                }
            }
            if (lrow == 0) {
                #pragma unroll
                for (int reg = 0; reg < 4; ++reg) {
                    int row = mh * 16 + quad * 4 + reg;
                    ML[(idx * 32 + row) * 2 + 0] = Mrow[reg];
                    ML[(idx * 32 + row) * 2 + 1] = Drow[reg];
                }
            }
        } else {
            #pragma unroll
            for (int df = 0; df < 8; ++df) {
                #pragma unroll
                for (int reg = 0; reg < 4; ++reg) {
                    float v = Obuf[(mh * 16 + quad * 4 + reg) * 128 + df * 16 + lrow]
                            + accO[df][reg] * myw[reg];
                    size_t o = ((size_t)(b * SEQ + R + quad * 4 + reg)) * HD + df * 16 + lrow;
                    out[o] = v;
                }
            }
        }
    }
}

// ---------------------------------------------------------------------------
// Kernel 3: split-K merge.  One float4 per thread; 524288 threads.
// ---------------------------------------------------------------------------
__global__ __launch_bounds__(256) void splitk_merge(
    const float* __restrict__ Opart, const float* __restrict__ ML,
    float* __restrict__ out)
{
    int tid = blockIdx.x * 256 + threadIdx.x;
    int row = tid >> 5, c4 = tid & 31;
    int b = row >> 11, r = row & 2047, s = r >> 5, rr = r & 31;
    int i0 = ((63 - s) << 4) + b;                   // h=0 block
    int i1 = i0 + 8;                                // h=1 block
    float m0 = ML[(i0 * 32 + rr) * 2], l0 = ML[(i0 * 32 + rr) * 2 + 1];
    float m1 = ML[(i1 * 32 + rr) * 2], l1 = ML[(i1 * 32 + rr) * 2 + 1];
    float M  = fmaxf(m0, m1);
    float w0 = __expf(m0 - M), w1 = __expf(m1 - M);
    float inv = 1.0f / (w0 * l0 + w1 * l1);
    float4 a  = *(const float4*)&Opart[((size_t)i0 * 32 + rr) * 128 + c4 * 4];
    float4 bb = *(const float4*)&Opart[((size_t)i1 * 32 + rr) * 128 + c4 * 4];
    float4 o;
    o.x = (w0 * a.x + w1 * bb.x) * inv;
    o.y = (w0 * a.y + w1 * bb.y) * inv;
    o.z = (w0 * a.z + w1 * bb.z) * inv;
    o.w = (w0 * a.w + w1 * bb.w) * inv;
    *(float4*)&out[(size_t)row * 128 + c4 * 4] = o;
}

// ---------------------------------------------------------------------------
extern "C" void kernel_launch(void* const* d_in, const int* in_sizes, int n_in,
                              void* d_out, int out_size, void* d_ws, size_t ws_size,
                              hipStream_t stream) {
    const float* x  = (const float*)d_in[0];
    const float* Wq = (const float*)d_in[1];
    const float* bq = (const float*)d_in[2];
    const float* Wk = (const float*)d_in[3];
    const float* bk = (const float*)d_in[4];
    const float* Wv = (const float*)d_in[5];
    const float* bv = (const float*)d_in[6];
    float* out = (float*)d_out;

    unsigned short* Qh  = (unsigned short*)d_ws;
    unsigned short* Ql  = Qh  + (size_t)M_TOT * HD;
    unsigned short* Kh  = Ql  + (size_t)M_TOT * HD;
    unsigned short* Kl  = Kh  + (size_t)M_TOT * HD;
    unsigned short* Vt  = Kl  + (size_t)M_TOT * HD;
    unsigned short* Wth = Vt  + (size_t)M_TOT * HD;
    unsigned short* Wtl = Wth + (size_t)3 * HD * DIM;
    float* Opart = (float*)(Wtl + (size_t)3 * HD * DIM);   // 1024 x 32 x 128 f32
    float* ML    = Opart + (size_t)1024 * 32 * 128;        // 1024 x 32 x 2 f32

    const size_t need = 22544384ULL + 16777216ULL + 262144ULL;   // 39.6 MB
    const int split = (ws_size >= need) ? 1 : 0;

    wt_prep<<<(3 * HD * DIM) / 256, 256, 0, stream>>>(Wq, Wk, Wv, Wth, Wtl);
    qkv_gemm<<<dim3(3, 256), 256, 0, stream>>>(x, Wth, Wtl, bq, bk, bv, Qh, Ql, Kh, Kl, Vt);
    flash_attn<<<split ? 1024 : 512, 256, 0, stream>>>(Qh, Ql, Kh, Kl, Vt, out, Opart, ML, split);
    if (split) splitk_merge<<<2048, 256, 0, stream>>>(Opart, ML, out);
}

// Round 6
// 246.021 us; speedup vs baseline: 1.1568x; 1.1568x over previous
//
#include <hip/hip_runtime.h>
#include <math.h>

#define SEQ 2048
#define DIM 1024
#define HD  128
#define NB  8
#define M_TOT (NB * SEQ)   // 16384

typedef __attribute__((ext_vector_type(8))) short   short8;   // 8 x bf16 (4 VGPRs)
typedef __attribute__((ext_vector_type(4))) float   floatx4;  // MFMA acc

__device__ __forceinline__ unsigned short f2bf(float f) {
    unsigned u = __builtin_bit_cast(unsigned, f);
    u += 0x7FFFu + ((u >> 16) & 1u);
    return (unsigned short)(u >> 16);
}
__device__ __forceinline__ float bf2f(unsigned short h) {
    unsigned u = ((unsigned)h) << 16;
    return __builtin_bit_cast(float, u);
}
__device__ __forceinline__ void async16(const void* g, void* l) {
    __builtin_amdgcn_global_load_lds(
        (const __attribute__((address_space(1))) unsigned int*)g,
        (__attribute__((address_space(3))) unsigned int*)l, 16, 0, 0);
}

#define MFMA16(a, b, c) __builtin_amdgcn_mfma_f32_16x16x32_bf16((a), (b), (c), 0, 0, 0)

// ---------------------------------------------------------------------------
// Kernel 0: W -> Wt (transposed, bf16 hi/lo split).  Wt[mat][n=128][k=1024]
// ---------------------------------------------------------------------------
__global__ __launch_bounds__(256) void wt_prep(
    const float* __restrict__ Wq, const float* __restrict__ Wk, const float* __restrict__ Wv,
    unsigned short* __restrict__ Wth, unsigned short* __restrict__ Wtl)
{
    int idx = blockIdx.x * 256 + threadIdx.x;       // [mat][n][k] flat
    int k   = idx & 1023;
    int n   = (idx >> 10) & 127;
    int mat = idx >> 17;
    const float* W = (mat == 0) ? Wq : (mat == 1) ? Wk : Wv;
    float v = W[k * HD + n];
    unsigned short hi = f2bf(v);
    Wth[idx] = hi;
    Wtl[idx] = f2bf(v - bf2f(hi));
}

// ---------------------------------------------------------------------------
// Kernel 1: QKV projection.  grid = (3 mats, 256 mtiles), 256 thr, 4 waves.
// BM=64, BN=128, BK=32, LDS double-buffered (2 x 24 KB), 3 blocks/CU.
// ALL staging is pure async16 issued right after the barrier; compute of the
// previous tile is the drain cover.  x staged as RAW FP32 (2 x 1KB sub-frags
// per 16-row frag, canonical lane*16 layout); hi/lo split happens at consume
// time in VGPRs (co-issues with MFMA from other waves).
// Frag ids per buf q: A = q*24 + mf*2+c (fp32, c=k-half); B = q*24+8+nf*2+p.
// ---------------------------------------------------------------------------
__global__ __launch_bounds__(256) void qkv_gemm(
    const float* __restrict__ x,
    const unsigned short* __restrict__ Wth, const unsigned short* __restrict__ Wtl,
    const float* __restrict__ bq, const float* __restrict__ bk, const float* __restrict__ bv,
    unsigned short* __restrict__ Qh, unsigned short* __restrict__ Ql,
    unsigned short* __restrict__ Kh, unsigned short* __restrict__ Kl,
    unsigned short* __restrict__ Vt)
{
    __shared__ short lds[48 * 512];                 // 48 KB

    const int t    = threadIdx.x;
    const int lane = t & 63;
    const int w    = t >> 6;
    const int lrow = lane & 15;
    const int quad = lane >> 4;

    const int mat = blockIdx.x;                     // 0=Q 1=K 2=V
    const int R0  = blockIdx.y * 64;
    const int mh  = w & 1;
    const int nh  = w >> 1;

    floatx4 acc[2][4];
    const floatx4 zf = {0.f, 0.f, 0.f, 0.f};
    #pragma unroll
    for (int i = 0; i < 2; ++i)
        #pragma unroll
        for (int j = 0; j < 4; ++j) acc[i][j] = zf;

    const size_t wmat = (size_t)mat * (HD * DIM);

    // wave w stages frag ids w*6 .. w*6+5  (24 frags total per buffer)
    auto stage = [&](int k0, int q) {
        #pragma unroll
        for (int i = 0; i < 6; ++i) {
            int id = w * 6 + i;
            const void* src;
            if (id < 8) {                           // A fp32 sub-frag: mf, c
                int mf = id >> 1, c = id & 1;
                src = x + (size_t)(R0 + mf * 16 + lrow) * DIM + k0 + quad * 8 + c * 4;
            } else {                                // B frag: nf, p
                int bid = id - 8, p = bid & 1, nf = bid >> 1;
                src = (p ? Wtl : Wth) + wmat
                    + (size_t)(nf * 16 + lrow) * DIM + k0 + quad * 8;
            }
            async16(src, &lds[(q * 24 + id) * 512 + lane * 8]);
        }
    };

    stage(0, 0);
    for (int it = 0; it < 32; ++it) {
        __syncthreads();                            // drains buf[it&1] staging
        if (it < 31) stage((it + 1) * 32, (it + 1) & 1);
        const int q = it & 1;

        // consume A: fp32 -> hi/lo split in regs
        short8 ah[2], al[2];
        #pragma unroll
        for (int mi = 0; mi < 2; ++mi) {
            int mf = 2 * mh + mi;
            const float* f0 = (const float*)&lds[(q * 24 + mf * 2 + 0) * 512];
            const float* f1 = (const float*)&lds[(q * 24 + mf * 2 + 1) * 512];
            float4 fa = *(const float4*)&f0[lane * 4];
            float4 fb = *(const float4*)&f1[lane * 4];
            float xv[8] = {fa.x, fa.y, fa.z, fa.w, fb.x, fb.y, fb.z, fb.w};
            #pragma unroll
            for (int i = 0; i < 8; ++i) {
                unsigned short h = f2bf(xv[i]);
                ah[mi][i] = (short)h;
                al[mi][i] = (short)f2bf(xv[i] - bf2f(h));
            }
        }
        #pragma unroll
        for (int ni = 0; ni < 4; ++ni) {
            int nf = nh * 4 + ni;
            short8 bh = *(short8*)&lds[(q * 24 + 8 + nf * 2 + 0) * 512 + lane * 8];
            #pragma unroll
            for (int mi = 0; mi < 2; ++mi)
                acc[mi][ni] = MFMA16(ah[mi], bh, acc[mi][ni]);
            if (mat < 2) {                          // uniform branch
                short8 bl = *(short8*)&lds[(q * 24 + 8 + nf * 2 + 1) * 512 + lane * 8];
                #pragma unroll
                for (int mi = 0; mi < 2; ++mi) {
                    acc[mi][ni] = MFMA16(ah[mi], bl, acc[mi][ni]);
                    acc[mi][ni] = MFMA16(al[mi], bh, acc[mi][ni]);
                }
            }
        }
    }

    // epilogue
    const float* bias = (mat == 0) ? bq : (mat == 1) ? bk : bv;
    #pragma unroll
    for (int ni = 0; ni < 4; ++ni) {
        int col = (nh * 4 + ni) * 16 + lrow;
        float bval = bias[col];
        #pragma unroll
        for (int mi = 0; mi < 2; ++mi) {
            #pragma unroll
            for (int reg = 0; reg < 4; ++reg) {
                int gm = R0 + (2 * mh + mi) * 16 + quad * 4 + reg;
                float v = acc[mi][ni][reg] + bval;
                if (mat == 0) {
                    v *= 32.0f;                     // fold sqrt(D)
                    unsigned short h = f2bf(v);
                    Qh[(size_t)gm * HD + col] = h;
                    Ql[(size_t)gm * HD + col] = f2bf(v - bf2f(h));
                } else if (mat == 1) {
                    unsigned short h = f2bf(v);
                    Kh[(size_t)gm * HD + col] = h;
                    Kl[(size_t)gm * HD + col] = f2bf(v - bf2f(h));
                } else {
                    int b = gm >> 11, s = gm & 2047;
                    Vt[((size_t)b * HD + col) * SEQ + s] = f2bf(v);
                }
            }
        }
    }
}

// ---------------------------------------------------------------------------
// Kernel 2: causal flash attention.  Strips of 64 Q-rows, 32-key tiles,
// double-buffered K/V staging, ONE barrier per tile (staging of tile t+1 is
// covered by compute of tile t).  Each wave owns 16 complete rows (no
// cross-wave softmax merge).  Split-K over the tile range (2 halves).
// grid (split=1) = 512: b=idx&7, h=(idx>>3)&1, s=31-(idx>>4) (heavy first).
// T = 2(s+1) tiles; half h covers [h*(s+1), h*(s+1)+(s+1)).
// LDS frags (1KB): buf q: K = q*24 + nt*8+kc*2+p (16) | V = q*24+16+df (8);
// P = 48 + w.  Total 52 KB -> 3 blocks/CU.
// ---------------------------------------------------------------------------
__global__ __launch_bounds__(256) void flash_attn(
    const unsigned short* __restrict__ Qh, const unsigned short* __restrict__ Ql,
    const unsigned short* __restrict__ Kh, const unsigned short* __restrict__ Kl,
    const unsigned short* __restrict__ Vt, float* __restrict__ out,
    float* __restrict__ Opart, float* __restrict__ ML, int split)
{
    __shared__ short lds[52 * 512];                 // 52 KB

    const int t    = threadIdx.x;
    const int lane = t & 63;
    const int w    = t >> 6;
    const int lrow = lane & 15;
    const int quad = lane >> 4;

    const int idx = blockIdx.x;
    const int b   = idx & 7;
    const int h   = split ? ((idx >> 3) & 1) : 0;
    const int s   = split ? (31 - (idx >> 4)) : (31 - (idx >> 3));
    const int t0  = split ? (h * (s + 1)) : 0;
    const int t1  = t0 + (split ? (s + 1) : (2 * (s + 1)));

    const int R = s * 64 + w * 16;                  // wave's 16 rows (batch-local)

    const size_t kbase = (size_t)b * SEQ * HD;
    const size_t vbase = (size_t)b * HD * SEQ;

    short8 qf[4][2];
    #pragma unroll
    for (int kc = 0; kc < 4; ++kc) {
        size_t off = kbase + (size_t)(R + lrow) * HD + kc * 32 + quad * 8;
        qf[kc][0] = *(const short8*)(Qh + off);
        qf[kc][1] = *(const short8*)(Ql + off);
    }

    const floatx4 zf = {0.f, 0.f, 0.f, 0.f};
    floatx4 accO[8];
    #pragma unroll
    for (int i = 0; i < 8; ++i) accO[i] = zf;
    float m_[4] = {-1e30f, -1e30f, -1e30f, -1e30f};
    float l_[4] = {0.f, 0.f, 0.f, 0.f};

    // wave w stages frag ids w*6 .. w*6+5 (24 frags per buffer)
    auto stage = [&](int tile, int q) {
        const int j0 = tile * 32;
        #pragma unroll
        for (int i = 0; i < 6; ++i) {
            int id = w * 6 + i;
            const unsigned short* src;
            if (id < 16) {                          // K frag: nt, kc, p
                int nt = id >> 3, kc = (id >> 1) & 3, p = id & 1;
                src = (p ? Kl : Kh) + kbase
                    + (size_t)(j0 + nt * 16 + lrow) * HD + kc * 32 + quad * 8;
            } else {                                // V frag: df
                int df = id - 16;
                src = Vt + vbase + (size_t)(df * 16 + lrow) * SEQ + j0 + quad * 8;
            }
            async16(src, &lds[(q * 24 + id) * 512 + lane * 8]);
        }
    };

    stage(t0, 0);
    for (int it = t0; it < t1; ++it) {
        __syncthreads();                            // drains staging of buf[(it-t0)&1]
        if (it + 1 < t1) stage(it + 1, (it + 1 - t0) & 1);
        const int q  = (it - t0) & 1;
        const int j0 = it * 32;

        if (j0 <= R + 15) {                         // tile not entirely above my rows
            // QK^T (bf16x3) over 32 keys
            floatx4 S[2] = {zf, zf};
            #pragma unroll
            for (int nt = 0; nt < 2; ++nt) {
                #pragma unroll
                for (int kc = 0; kc < 4; ++kc) {
                    short8 khf = *(short8*)&lds[(q * 24 + nt * 8 + kc * 2 + 0) * 512 + lane * 8];
                    short8 klf = *(short8*)&lds[(q * 24 + nt * 8 + kc * 2 + 1) * 512 + lane * 8];
                    S[nt] = MFMA16(qf[kc][0], khf, S[nt]);
                    S[nt] = MFMA16(qf[kc][0], klf, S[nt]);
                    S[nt] = MFMA16(qf[kc][1], khf, S[nt]);
                }
            }
            // causal mask (diagonal tiles only)
            if (j0 + 31 > R) {
                #pragma unroll
                for (int nt = 0; nt < 2; ++nt) {
                    int key = j0 + nt * 16 + lrow;
                    #pragma unroll
                    for (int reg = 0; reg < 4; ++reg) {
                        if (key > R + quad * 4 + reg) S[nt][reg] = -INFINITY;
                    }
                }
            }
            // online softmax (rows fully owned by this wave)
            float alpha[4];
            #pragma unroll
            for (int reg = 0; reg < 4; ++reg) {
                float mx = fmaxf(S[0][reg], S[1][reg]);
                #pragma unroll
                for (int hh = 1; hh < 16; hh <<= 1) mx = fmaxf(mx, __shfl_xor(mx, hh));
                float mnew = fmaxf(fmaxf(m_[reg], mx), -1e30f);
                alpha[reg] = __expf(m_[reg] - mnew);
                m_[reg] = mnew;
                float p0 = __expf(S[0][reg] - mnew);
                float p1 = __expf(S[1][reg] - mnew);
                S[0][reg] = p0; S[1][reg] = p1;
                float ls = p0 + p1;
                #pragma unroll
                for (int hh = 1; hh < 16; hh <<= 1) ls += __shfl_xor(ls, hh);
                l_[reg] = l_[reg] * alpha[reg] + ls;
            }
            #pragma unroll
            for (int i = 0; i < 8; ++i)
                #pragma unroll
                for (int reg = 0; reg < 4; ++reg) accO[i][reg] *= alpha[reg];

            // P: C-layout regs -> A-layout LDS (same-wave round trip)
            #pragma unroll
            for (int nt = 0; nt < 2; ++nt) {
                #pragma unroll
                for (int reg = 0; reg < 4; ++reg) {
                    int kloc = nt * 16 + lrow;       // 0..31
                    int jj = kloc & 7, q2 = (kloc >> 3) & 3;
                    int lane2 = (quad * 4 + reg) + (q2 << 4);
                    lds[(48 + w) * 512 + lane2 * 8 + jj] = (short)f2bf(S[nt][reg]);
                }
            }
            short8 pf = *(short8*)&lds[(48 + w) * 512 + lane * 8];
            #pragma unroll
            for (int df = 0; df < 8; ++df) {
                short8 vf = *(short8*)&lds[(q * 24 + 16 + df) * 512 + lane * 8];
                accO[df] = MFMA16(pf, vf, accO[df]);
            }
        }
    }

    // epilogue (wave owns rows completely)
    if (split) {
        float* op = Opart + (size_t)idx * (64 * 128);
        #pragma unroll
        for (int df = 0; df < 8; ++df) {
            #pragma unroll
            for (int reg = 0; reg < 4; ++reg) {
                int rl = w * 16 + quad * 4 + reg;
                op[rl * 128 + df * 16 + lrow] = accO[df][reg];
            }
        }
        if (lrow == 0) {
            #pragma unroll
            for (int reg = 0; reg < 4; ++reg) {
                int rl = w * 16 + quad * 4 + reg;
                ML[(idx * 64 + rl) * 2 + 0] = m_[reg];
                ML[(idx * 64 + rl) * 2 + 1] = l_[reg];
            }
        }
    } else {
        float inv[4];
        #pragma unroll
        for (int reg = 0; reg < 4; ++reg) inv[reg] = 1.0f / l_[reg];
        #pragma unroll
        for (int df = 0; df < 8; ++df) {
            #pragma unroll
            for (int reg = 0; reg < 4; ++reg) {
                size_t o = ((size_t)(b * SEQ + R + quad * 4 + reg)) * HD + df * 16 + lrow;
                out[o] = accO[df][reg] * inv[reg];
            }
        }
    }
}

// ---------------------------------------------------------------------------
// Kernel 3: split-K merge.  One float4 per thread; 524288 threads.
// ---------------------------------------------------------------------------
__global__ __launch_bounds__(256) void splitk_merge(
    const float* __restrict__ Opart, const float* __restrict__ ML,
    float* __restrict__ out)
{
    int tid = blockIdx.x * 256 + threadIdx.x;
    int row = tid >> 5, c4 = tid & 31;
    int b = row >> 11, r = row & 2047, s = r >> 6, rl = r & 63;
    int i0 = ((31 - s) << 4) + b;                   // h=0 block
    int i1 = i0 + 8;                                // h=1 block
    float m0 = ML[(i0 * 64 + rl) * 2], l0 = ML[(i0 * 64 + rl) * 2 + 1];
    float m1 = ML[(i1 * 64 + rl) * 2], l1 = ML[(i1 * 64 + rl) * 2 + 1];
    float M  = fmaxf(m0, m1);
    float w0 = __expf(m0 - M), w1 = __expf(m1 - M);
    float inv = 1.0f / (w0 * l0 + w1 * l1);
    float4 a  = *(const float4*)&Opart[((size_t)i0 * 64 + rl) * 128 + c4 * 4];
    float4 bb = *(const float4*)&Opart[((size_t)i1 * 64 + rl) * 128 + c4 * 4];
    float4 o;
    o.x = (w0 * a.x + w1 * bb.x) * inv;
    o.y = (w0 * a.y + w1 * bb.y) * inv;
    o.z = (w0 * a.z + w1 * bb.z) * inv;
    o.w = (w0 * a.w + w1 * bb.w) * inv;
    *(float4*)&out[(size_t)row * 128 + c4 * 4] = o;
}

// ---------------------------------------------------------------------------
extern "C" void kernel_launch(void* const* d_in, const int* in_sizes, int n_in,
                              void* d_out, int out_size, void* d_ws, size_t ws_size,
                              hipStream_t stream) {
    const float* x  = (const float*)d_in[0];
    const float* Wq = (const float*)d_in[1];
    const float* bq = (const float*)d_in[2];
    const float* Wk = (const float*)d_in[3];
    const float* bk = (const float*)d_in[4];
    const float* Wv = (const float*)d_in[5];
    const float* bv = (const float*)d_in[6];
    float* out = (float*)d_out;

    unsigned short* Qh  = (unsigned short*)d_ws;
    unsigned short* Ql  = Qh  + (size_t)M_TOT * HD;
    unsigned short* Kh  = Ql  + (size_t)M_TOT * HD;
    unsigned short* Kl  = Kh  + (size_t)M_TOT * HD;
    unsigned short* Vt  = Kl  + (size_t)M_TOT * HD;
    unsigned short* Wth = Vt  + (size_t)M_TOT * HD;
    unsigned short* Wtl = Wth + (size_t)3 * HD * DIM;
    float* Opart = (float*)(Wtl + (size_t)3 * HD * DIM);   // 512 x 64 x 128 f32
    float* ML    = Opart + (size_t)512 * 64 * 128;         // 512 x 64 x 2 f32

    const size_t need = 22544384ULL + 16777216ULL + 262144ULL;   // 39.6 MB
    const int split = (ws_size >= need) ? 1 : 0;

    wt_prep<<<(3 * HD * DIM) / 256, 256, 0, stream>>>(Wq, Wk, Wv, Wth, Wtl);
    qkv_gemm<<<dim3(3, 256), 256, 0, stream>>>(x, Wth, Wtl, bq, bk, bv, Qh, Ql, Kh, Kl, Vt);
    flash_attn<<<split ? 512 : 256, 256, 0, stream>>>(Qh, Ql, Kh, Kl, Vt, out, Opart, ML, split);
    if (split) splitk_merge<<<2048, 256, 0, stream>>>(Opart, ML, out);
}